// Round 5
// baseline (2121.101 us; speedup 1.0000x reference)
//
#include <hip/hip_runtime.h>

// RNNDoubleStacked: P=4096 particles, F=128 max features (ragged), H=128 hidden.
// Phase A (net1_kernel): unchanged (one block/particle, W row in VGPRs, h dbuf in
//   LDS, early exit at len; tail writes U = h1@W_ih2^T + biases into d_ws).
// Phase B (net2_kernel): R4 post-mortem: step time ~967 cyc was dominated by the
//   s_waitcnt vmcnt(0) that __syncthreads emits before s_barrier — it drained the
//   same-step U prefetch load (~600-900 cyc L2-miss latency exposed EVERY step).
//   Fix: raw barrier `s_waitcnt lgkmcnt(0); s_barrier` via inline asm ("memory"
//   clobber orders LDS ops; writer-side lgkm drain publishes h before the
//   barrier) -> global loads stay in flight across steps. U prefetch deepened to
//   4 steps (~1600 cyc slack > ~900 cyc HBM latency). Dataflow otherwise = R4:
//   lane=(og,jg), 4 outputs x 16-float slice, 4 rotated b128 reads, 64 FMA,
//   3-stage reduce-scatter, 1 tanh/lane, conflict-free writes.

constexpr int PN = 4096;
constexpr int FN = 128;
constexpr int HN = 128;

__device__ __forceinline__ float fast_tanh(float x) {
    // tanh(x) = 1 - 2/(exp(2x)+1); correct +-1 limits via __expf saturation.
    float e = __expf(2.0f * x);
    return 1.0f - 2.0f / (e + 1.0f);
}

// Raw workgroup barrier WITHOUT the vmcnt(0) drain __syncthreads would emit.
// lgkmcnt(0) first: this wave's ds_write has landed before it signals arrival.
// "memory" clobber: compiler may not move LDS accesses across this point.
__device__ __forceinline__ void lds_barrier() {
    asm volatile("s_waitcnt lgkmcnt(0)\n\ts_barrier" ::: "memory");
}

__global__ __launch_bounds__(128) void net1_kernel(
    const float* __restrict__ event,
    const int*   __restrict__ lengths,
    const float* __restrict__ W_ih1,
    const float* __restrict__ W_hh1,
    const float* __restrict__ b_ih1,
    const float* __restrict__ b_hh1,
    const float* __restrict__ W_ih2,
    const float* __restrict__ b_ih2,
    const float* __restrict__ b_hh2,
    float* __restrict__ U)
{
    const int p = blockIdx.x;
    const int i = threadIdx.x;                 // output row 0..127

    __shared__ float h[2][HN];                 // double-buffered hidden state
    __shared__ float ev[FN];                   // this particle's input sequence

    ev[i]   = event[p * FN + i];               // coalesced (event is [P,F,1])
    h[0][i] = 0.0f;

    // W_hh1 row i in registers (128 VGPRs) — reused across all steps.
    float w[HN];
    {
        const float4* wrow = reinterpret_cast<const float4*>(W_hh1 + i * HN);
        #pragma unroll
        for (int k = 0; k < HN / 4; ++k) {
            float4 v = wrow[k];
            w[4*k+0] = v.x; w[4*k+1] = v.y; w[4*k+2] = v.z; w[4*k+3] = v.w;
        }
    }
    const float wx   = W_ih1[i];               // W_ih1 is [H,1]
    const float bias = b_ih1[i] + b_hh1[i];
    const int   len  = lengths[p];             // uniform across block, in [1,127)

    __syncthreads();

    // Reference masks updates at t >= len (h frozen) -> just stop at len.
    for (int t = 0; t < len; ++t) {
        const int cur = t & 1;
        const float x = ev[t];                 // LDS broadcast
        float a0 = fmaf(wx, x, bias), a1 = 0.f, a2 = 0.f, a3 = 0.f;
        const float4* h4 = reinterpret_cast<const float4*>(h[cur]);
        #pragma unroll
        for (int k = 0; k < HN / 4; ++k) {
            float4 hv = h4[k];                 // same addr all lanes -> broadcast
            a0 = fmaf(w[4*k+0], hv.x, a0);
            a1 = fmaf(w[4*k+1], hv.y, a1);
            a2 = fmaf(w[4*k+2], hv.z, a2);
            a3 = fmaf(w[4*k+3], hv.w, a3);
        }
        h[cur ^ 1][i] = fast_tanh((a0 + a1) + (a2 + a3));
        lds_barrier();                         // no vmem in flight here; cheap sync
    }

    // Tail: U[p][i] = h1 . W_ih2_row_i + b_ih2[i] + b_hh2[i]  (hoisted out of net2)
    {
        const float4* h4 = reinterpret_cast<const float4*>(h[len & 1]);
        const float4* w2 = reinterpret_cast<const float4*>(W_ih2 + i * HN);
        float a0 = b_ih2[i] + b_hh2[i], a1 = 0.f, a2 = 0.f, a3 = 0.f;
        #pragma unroll
        for (int k = 0; k < HN / 4; ++k) {
            float4 hv = h4[k];
            float4 wv = w2[k];
            a0 = fmaf(wv.x, hv.x, a0);
            a1 = fmaf(wv.y, hv.y, a1);
            a2 = fmaf(wv.z, hv.z, a2);
            a3 = fmaf(wv.w, hv.w, a3);
        }
        U[p * HN + i] = (a0 + a1) + (a2 + a3); // coalesced
    }
}

__global__ __launch_bounds__(256) void net2_kernel(
    const float* __restrict__ U,
    const float* __restrict__ W_hh2,
    float* __restrict__ out)
{
    const int tid  = threadIdx.x;
    const int wv   = tid >> 6;                 // wave 0..3
    const int lane = tid & 63;
    const int jg   = lane & 7;                 // inner group: h slice [jg*16, jg*16+16)
    const int ogl  = lane >> 3;                // output group within wave: 0..7
    const int og   = (wv << 3) + ogl;          // output group 0..31 (4 outputs each)
    const int rot  = jg >> 1;                  // bank-decorrelation rotation 0..3

    // After reduce-scatter this lane holds output og*4 + cidx (pairs jg, jg^1 dup).
    const int cidx = ((jg >> 2) & 1) * 2 + ((jg >> 1) & 1);
    const int oi_w = og * 4 + cidx;

    __shared__ float h[2][HN];                 // double-buffered hidden state

    // Weights w[c][4t+e] = W_hh2[og*4+c][jg*16 + 4*((t+rot)&3) + e]: the read
    // rotation is baked into the LOAD order so FMA reg indices stay static.
    float w[4][16];
    #pragma unroll
    for (int c = 0; c < 4; ++c) {
        const float* row = W_hh2 + (og * 4 + c) * HN + jg * 16;
        #pragma unroll
        for (int t = 0; t < 4; ++t) {
            const int krot = (t + rot) & 3;
            float4 v = *reinterpret_cast<const float4*>(row + 4 * krot);
            w[c][4*t+0] = v.x; w[c][4*t+1] = v.y;
            w[c][4*t+2] = v.z; w[c][4*t+3] = v.w;
        }
    }

    // 4-deep U prefetch pipe (per-lane column oi_w; jg-pairs duplicate).
    const float* Up = U + oi_w;
    float u0 = Up[0];
    float u1 = Up[1 * HN];
    float u2 = Up[2 * HN];
    float u3 = Up[3 * HN];
    const float* pf = Up + 4 * HN;             // next row to fetch

    if (tid < HN) h[0][tid] = 0.0f;
    __syncthreads();                           // one-time full drain is fine here

    for (int p = 0; p < PN; ++p) {
        const int cur = p & 1;
        const float u_cur = u0;
        u0 = u1; u1 = u2; u2 = u3;             // rotate 4-deep pipe
        u3 = *pf;                              // load U[min(p+4, PN-1)]
        if (p + 5 < PN) pf += HN;              // uniform scalar pointer bump

        // 4 b128 reads of this lane's 16-float h slice, rotated order:
        // slot t reads words jg*16 + 4*((t+rot)&3) -> unique addrs spread over
        // disjoint bank quads -> conflict-free. Each read feeds 16 FMAs.
        const float* base = &h[cur][jg * 16];
        float s0 = 0.f, s1 = 0.f, s2 = 0.f, s3 = 0.f;
        #pragma unroll
        for (int t = 0; t < 4; ++t) {
            const int krot = (t + rot) & 3;    // runtime only in the ADDRESS
            float4 hv = *reinterpret_cast<const float4*>(base + 4 * krot);
            s0 = fmaf(w[0][4*t+0], hv.x, s0); s0 = fmaf(w[0][4*t+1], hv.y, s0);
            s0 = fmaf(w[0][4*t+2], hv.z, s0); s0 = fmaf(w[0][4*t+3], hv.w, s0);
            s1 = fmaf(w[1][4*t+0], hv.x, s1); s1 = fmaf(w[1][4*t+1], hv.y, s1);
            s1 = fmaf(w[1][4*t+2], hv.z, s1); s1 = fmaf(w[1][4*t+3], hv.w, s1);
            s2 = fmaf(w[2][4*t+0], hv.x, s2); s2 = fmaf(w[2][4*t+1], hv.y, s2);
            s2 = fmaf(w[2][4*t+2], hv.z, s2); s2 = fmaf(w[2][4*t+3], hv.w, s2);
            s3 = fmaf(w[3][4*t+0], hv.x, s3); s3 = fmaf(w[3][4*t+1], hv.y, s3);
            s3 = fmaf(w[3][4*t+2], hv.z, s3); s3 = fmaf(w[3][4*t+3], hv.w, s3);
        }

        // Reduce-scatter over the 8 jg lanes: stage keeps half, ships half.
        const bool lo4 = (jg & 4) == 0;
        float t0 = lo4 ? s2 : s0;              // what I send at stage 1
        float t1 = lo4 ? s3 : s1;
        float x0 = (lo4 ? s0 : s2) + __shfl_xor(t0, 4);
        float x1 = (lo4 ? s1 : s3) + __shfl_xor(t1, 4);
        const bool lo2 = (jg & 2) == 0;
        float t2 = lo2 ? x1 : x0;              // what I send at stage 2
        float z  = (lo2 ? x0 : x1) + __shfl_xor(t2, 2);
        z += __shfl_xor(z, 1);                 // full sum; pairs jg, jg^1 duplicate

        const float hn = fast_tanh(z + u_cur);
        if ((jg & 1) == 0) h[cur ^ 1][oi_w] = hn;  // 16 lanes/wave, distinct banks
        lds_barrier();                         // NO vmcnt drain: prefetch stays in flight
    }

    if (tid < HN) out[tid] = h[PN & 1][tid];   // PN even -> result in h[0]
}

extern "C" void kernel_launch(void* const* d_in, const int* in_sizes, int n_in,
                              void* d_out, int out_size, void* d_ws, size_t ws_size,
                              hipStream_t stream)
{
    const float* event   = (const float*)d_in[0];
    const int*   lengths = (const int*)  d_in[1];
    const float* W_ih1   = (const float*)d_in[2];
    const float* W_hh1   = (const float*)d_in[3];
    const float* b_ih1   = (const float*)d_in[4];
    const float* b_hh1   = (const float*)d_in[5];
    const float* W_ih2   = (const float*)d_in[6];
    const float* W_hh2   = (const float*)d_in[7];
    const float* b_ih2   = (const float*)d_in[8];
    const float* b_hh2   = (const float*)d_in[9];
    float* out = (float*)d_out;                // 128 floats
    float* U   = (float*)d_ws;                 // PN*HN floats = 2 MB scratch

    hipLaunchKernelGGL(net1_kernel, dim3(PN), dim3(HN), 0, stream,
                       event, lengths, W_ih1, W_hh1, b_ih1, b_hh1,
                       W_ih2, b_ih2, b_hh2, U);
    hipLaunchKernelGGL(net2_kernel, dim3(1), dim3(256), 0, stream,
                       U, W_hh2, out);
}

// Round 6
// 2093.398 us; speedup vs baseline: 1.0132x; 1.0132x over previous
//
#include <hip/hip_runtime.h>

// RNNDoubleStacked: P=4096 particles, F=128 max features (ragged), H=128 hidden.
// Phase A (net1_kernel): unchanged (one block/particle, W row in VGPRs, h dbuf in
//   LDS, early exit at len; tail writes U = h1@W_ih2^T + biases into d_ws).
// Phase B (net2_kernel): R2-R5 step time pinned at ~1000 cyc across four
//   dataflows; the invariant is a per-step GLOBAL load of U whose latency the
//   compiler's register-dependence wait exposes every iteration. This round
//   removes all global traffic from the step loop: U is staged into LDS in
//   64-step chunks, double-buffered. Chunk loads are issued (to registers) at
//   chunk START and written to LDS at chunk END (T14 issue-early/write-late),
//   so ~900-cyc HBM latency amortizes over 64 steps (~30K cyc of slack).
//   Step dataflow identical to R5: lane=(og,jg), 4 rotated b128 h-reads,
//   64 FMA, 3-stage reduce-scatter, 1 tanh/lane, raw lgkm-only barrier.

constexpr int PN = 4096;
constexpr int FN = 128;
constexpr int HN = 128;
constexpr int CH  = 64;            // steps per staged U chunk
constexpr int NCH = PN / CH;       // 64 chunks

__device__ __forceinline__ float fast_tanh(float x) {
    // tanh(x) = 1 - 2/(exp(2x)+1); correct +-1 limits via __expf saturation.
    float e = __expf(2.0f * x);
    return 1.0f - 2.0f / (e + 1.0f);
}

// Raw workgroup barrier WITHOUT a vmcnt(0) drain: lgkmcnt(0) publishes this
// wave's ds_write before it signals arrival; "memory" clobber pins LDS ops
// (and pins the chunk-staging global loads/writes on their side of the loop).
__device__ __forceinline__ void lds_barrier() {
    asm volatile("s_waitcnt lgkmcnt(0)\n\ts_barrier" ::: "memory");
}

__global__ __launch_bounds__(128) void net1_kernel(
    const float* __restrict__ event,
    const int*   __restrict__ lengths,
    const float* __restrict__ W_ih1,
    const float* __restrict__ W_hh1,
    const float* __restrict__ b_ih1,
    const float* __restrict__ b_hh1,
    const float* __restrict__ W_ih2,
    const float* __restrict__ b_ih2,
    const float* __restrict__ b_hh2,
    float* __restrict__ U)
{
    const int p = blockIdx.x;
    const int i = threadIdx.x;                 // output row 0..127

    __shared__ float h[2][HN];                 // double-buffered hidden state
    __shared__ float ev[FN];                   // this particle's input sequence

    ev[i]   = event[p * FN + i];               // coalesced (event is [P,F,1])
    h[0][i] = 0.0f;

    // W_hh1 row i in registers (128 VGPRs) — reused across all steps.
    float w[HN];
    {
        const float4* wrow = reinterpret_cast<const float4*>(W_hh1 + i * HN);
        #pragma unroll
        for (int k = 0; k < HN / 4; ++k) {
            float4 v = wrow[k];
            w[4*k+0] = v.x; w[4*k+1] = v.y; w[4*k+2] = v.z; w[4*k+3] = v.w;
        }
    }
    const float wx   = W_ih1[i];               // W_ih1 is [H,1]
    const float bias = b_ih1[i] + b_hh1[i];
    const int   len  = lengths[p];             // uniform across block, in [1,127)

    __syncthreads();

    // Reference masks updates at t >= len (h frozen) -> just stop at len.
    for (int t = 0; t < len; ++t) {
        const int cur = t & 1;
        const float x = ev[t];                 // LDS broadcast
        float a0 = fmaf(wx, x, bias), a1 = 0.f, a2 = 0.f, a3 = 0.f;
        const float4* h4 = reinterpret_cast<const float4*>(h[cur]);
        #pragma unroll
        for (int k = 0; k < HN / 4; ++k) {
            float4 hv = h4[k];                 // same addr all lanes -> broadcast
            a0 = fmaf(w[4*k+0], hv.x, a0);
            a1 = fmaf(w[4*k+1], hv.y, a1);
            a2 = fmaf(w[4*k+2], hv.z, a2);
            a3 = fmaf(w[4*k+3], hv.w, a3);
        }
        h[cur ^ 1][i] = fast_tanh((a0 + a1) + (a2 + a3));
        lds_barrier();                         // no vmem in flight here; cheap sync
    }

    // Tail: U[p][i] = h1 . W_ih2_row_i + b_ih2[i] + b_hh2[i]  (hoisted out of net2)
    {
        const float4* h4 = reinterpret_cast<const float4*>(h[len & 1]);
        const float4* w2 = reinterpret_cast<const float4*>(W_ih2 + i * HN);
        float a0 = b_ih2[i] + b_hh2[i], a1 = 0.f, a2 = 0.f, a3 = 0.f;
        #pragma unroll
        for (int k = 0; k < HN / 4; ++k) {
            float4 hv = h4[k];
            float4 wv = w2[k];
            a0 = fmaf(wv.x, hv.x, a0);
            a1 = fmaf(wv.y, hv.y, a1);
            a2 = fmaf(wv.z, hv.z, a2);
            a3 = fmaf(wv.w, hv.w, a3);
        }
        U[p * HN + i] = (a0 + a1) + (a2 + a3); // coalesced
    }
}

__global__ __launch_bounds__(256) void net2_kernel(
    const float* __restrict__ U,
    const float* __restrict__ W_hh2,
    float* __restrict__ out)
{
    const int tid  = threadIdx.x;
    const int wv   = tid >> 6;                 // wave 0..3
    const int lane = tid & 63;
    const int jg   = lane & 7;                 // inner group: h slice [jg*16, jg*16+16)
    const int ogl  = lane >> 3;                // output group within wave: 0..7
    const int og   = (wv << 3) + ogl;          // output group 0..31 (4 outputs each)
    const int rot  = jg >> 1;                  // bank-decorrelation rotation 0..3

    // After reduce-scatter this lane holds output og*4 + cidx (pairs jg, jg^1 dup).
    const int cidx = ((jg >> 2) & 1) * 2 + ((jg >> 1) & 1);
    const int oi_w = og * 4 + cidx;

    __shared__ float h[2][HN];                 // double-buffered hidden state
    __shared__ float Ulds[2][CH * HN];         // double-buffered U panel (2 x 32 KB)

    // Weights w[c][4t+e] = W_hh2[og*4+c][jg*16 + 4*((t+rot)&3) + e]: the read
    // rotation is baked into the LOAD order so FMA reg indices stay static.
    float w[4][16];
    #pragma unroll
    for (int c = 0; c < 4; ++c) {
        const float* row = W_hh2 + (og * 4 + c) * HN + jg * 16;
        #pragma unroll
        for (int t = 0; t < 4; ++t) {
            const int krot = (t + rot) & 3;
            float4 v = *reinterpret_cast<const float4*>(row + 4 * krot);
            w[c][4*t+0] = v.x; w[c][4*t+1] = v.y;
            w[c][4*t+2] = v.z; w[c][4*t+3] = v.w;
        }
    }

    // Stage chunk 0 synchronously (8 coalesced float4 per thread).
    {
        const float4* g = reinterpret_cast<const float4*>(U);
        float4*       l = reinterpret_cast<float4*>(&Ulds[0][0]);
        #pragma unroll
        for (int r = 0; r < 8; ++r) l[r * 256 + tid] = g[r * 256 + tid];
    }
    if (tid < HN) h[0][tid] = 0.0f;
    __syncthreads();

    int buf = 0;
    for (int c = 0; c < NCH; ++c) {
        const int nb = buf ^ 1;

        // Issue-early: global loads for chunk c+1 into registers. They stay in
        // flight across the whole chunk (~30K cyc of slack >> HBM latency).
        float4 st[8];
        const int cg = (c + 1 < NCH) ? (c + 1) : c;   // last chunk: harmless reload
        {
            const float4* gsrc = reinterpret_cast<const float4*>(U + cg * CH * HN);
            #pragma unroll
            for (int r = 0; r < 8; ++r) st[r] = gsrc[r * 256 + tid];
        }

        for (int s = 0; s < CH; ++s) {
            const int hc = s & 1;              // CH even -> parity restarts at 0
            const float u_cur = Ulds[buf][s * HN + oi_w];  // ds_read_b32, banks 0..31

            // 4 b128 reads of this lane's 16-float h slice, rotated order ->
            // conflict-free. Each read feeds 16 FMAs.
            const float* base = &h[hc][jg * 16];
            float s0 = 0.f, s1 = 0.f, s2 = 0.f, s3 = 0.f;
            #pragma unroll
            for (int t = 0; t < 4; ++t) {
                const int krot = (t + rot) & 3;    // runtime only in the ADDRESS
                float4 hv = *reinterpret_cast<const float4*>(base + 4 * krot);
                s0 = fmaf(w[0][4*t+0], hv.x, s0); s0 = fmaf(w[0][4*t+1], hv.y, s0);
                s0 = fmaf(w[0][4*t+2], hv.z, s0); s0 = fmaf(w[0][4*t+3], hv.w, s0);
                s1 = fmaf(w[1][4*t+0], hv.x, s1); s1 = fmaf(w[1][4*t+1], hv.y, s1);
                s1 = fmaf(w[1][4*t+2], hv.z, s1); s1 = fmaf(w[1][4*t+3], hv.w, s1);
                s2 = fmaf(w[2][4*t+0], hv.x, s2); s2 = fmaf(w[2][4*t+1], hv.y, s2);
                s2 = fmaf(w[2][4*t+2], hv.z, s2); s2 = fmaf(w[2][4*t+3], hv.w, s2);
                s3 = fmaf(w[3][4*t+0], hv.x, s3); s3 = fmaf(w[3][4*t+1], hv.y, s3);
                s3 = fmaf(w[3][4*t+2], hv.z, s3); s3 = fmaf(w[3][4*t+3], hv.w, s3);
            }

            // Reduce-scatter over the 8 jg lanes: stage keeps half, ships half.
            const bool lo4 = (jg & 4) == 0;
            float t0 = lo4 ? s2 : s0;
            float t1 = lo4 ? s3 : s1;
            float x0 = (lo4 ? s0 : s2) + __shfl_xor(t0, 4);
            float x1 = (lo4 ? s1 : s3) + __shfl_xor(t1, 4);
            const bool lo2 = (jg & 2) == 0;
            float t2 = lo2 ? x1 : x0;
            float z  = (lo2 ? x0 : x1) + __shfl_xor(t2, 2);
            z += __shfl_xor(z, 1);             // full sum; pairs jg, jg^1 duplicate

            const float hn = fast_tanh(z + u_cur);
            if ((jg & 1) == 0) h[hc ^ 1][oi_w] = hn;   // 16 lanes/wave, distinct banks
            lds_barrier();                     // lgkm-only: nothing global in flight
        }

        // Write-late: publish staged chunk to the back buffer. The compiler's
        // vmcnt wait here is ~free (loads issued 64 steps ago). One full
        // barrier per 64 steps.
        {
            float4* ldst = reinterpret_cast<float4*>(&Ulds[nb][0]);
            #pragma unroll
            for (int r = 0; r < 8; ++r) ldst[r * 256 + tid] = st[r];
        }
        __syncthreads();
        buf = nb;
    }

    if (tid < HN) out[tid] = h[0][tid];        // PN even -> result in h[0]
}

extern "C" void kernel_launch(void* const* d_in, const int* in_sizes, int n_in,
                              void* d_out, int out_size, void* d_ws, size_t ws_size,
                              hipStream_t stream)
{
    const float* event   = (const float*)d_in[0];
    const int*   lengths = (const int*)  d_in[1];
    const float* W_ih1   = (const float*)d_in[2];
    const float* W_hh1   = (const float*)d_in[3];
    const float* b_ih1   = (const float*)d_in[4];
    const float* b_hh1   = (const float*)d_in[5];
    const float* W_ih2   = (const float*)d_in[6];
    const float* W_hh2   = (const float*)d_in[7];
    const float* b_ih2   = (const float*)d_in[8];
    const float* b_hh2   = (const float*)d_in[9];
    float* out = (float*)d_out;                // 128 floats
    float* U   = (float*)d_ws;                 // PN*HN floats = 2 MB scratch

    hipLaunchKernelGGL(net1_kernel, dim3(PN), dim3(HN), 0, stream,
                       event, lengths, W_ih1, W_hh1, b_ih1, b_hh1,
                       W_ih2, b_ih2, b_hh2, U);
    hipLaunchKernelGGL(net2_kernel, dim3(1), dim3(256), 0, stream,
                       U, W_hh2, out);
}

// Round 7
// 1803.883 us; speedup vs baseline: 1.1759x; 1.1605x over previous
//
#include <hip/hip_runtime.h>

// RNNDoubleStacked: P=4096 particles, F=128 max features (ragged), H=128 hidden.
// Phase A (net1_kernel): unchanged (one block/particle, W row in VGPRs, h dbuf in
//   LDS, early exit at len; tail writes U = h1@W_ih2^T + biases into d_ws).
// Phase B (net2_kernel): R6 post-mortem: step time ~1000 cyc across five
//   dataflows; the last unexamined constant was __shfl_xor = ds_bpermute (LDS
//   pipe, ~60-100 cyc latency EACH; three dependent per step ≈ 280 cyc).
//   This round: reduce done entirely with DPP (VALU, ~4-8 cyc/stage):
//     xor1 -> quad_perm 0xB1, xor2 -> quad_perm 0x4E,
//     xor4 -> row_shl:4 / row_shr:4 + per-lane select (partners stay within
//             the 16-lane DPP row because jg = lane bits 0..2).
//   Identical pairing order -> bit-identical sums. All else identical to R6:
//   chunked LDS U staging (64-step dbuf panels, issue-early/write-late),
//   lane=(og,jg), 4 rotated b128 h-reads, 64 FMA, raw lgkm-only barrier.

constexpr int PN = 4096;
constexpr int FN = 128;
constexpr int HN = 128;
constexpr int CH  = 64;            // steps per staged U chunk
constexpr int NCH = PN / CH;       // 64 chunks

__device__ __forceinline__ float fast_tanh(float x) {
    // tanh(x) = 1 - 2/(exp(2x)+1); correct +-1 limits via __expf saturation.
    float e = __expf(2.0f * x);
    return 1.0f - 2.0f / (e + 1.0f);
}

// Raw workgroup barrier WITHOUT a vmcnt(0) drain: lgkmcnt(0) publishes this
// wave's ds_write before it signals arrival; "memory" clobber pins LDS ops.
__device__ __forceinline__ void lds_barrier() {
    asm volatile("s_waitcnt lgkmcnt(0)\n\ts_barrier" ::: "memory");
}

// --- DPP cross-lane ops (VALU latency, replaces ds_bpermute-based __shfl_xor) ---
__device__ __forceinline__ float dpp_xor1(float x) {      // value of lane^1
    return __int_as_float(__builtin_amdgcn_update_dpp(
        0, __float_as_int(x), 0xB1 /*quad_perm 1,0,3,2*/, 0xF, 0xF, true));
}
__device__ __forceinline__ float dpp_xor2(float x) {      // value of lane^2
    return __int_as_float(__builtin_amdgcn_update_dpp(
        0, __float_as_int(x), 0x4E /*quad_perm 2,3,0,1*/, 0xF, 0xF, true));
}
__device__ __forceinline__ float dpp_xor4(float x, bool hi4) { // value of lane^4
    // row_shl:4 -> res[n]=src[n+4] (valid for n&4==0); row_shr:4 -> src[n-4].
    int a = __builtin_amdgcn_update_dpp(0, __float_as_int(x), 0x104, 0xF, 0xF, true);
    int b = __builtin_amdgcn_update_dpp(0, __float_as_int(x), 0x114, 0xF, 0xF, true);
    return __int_as_float(hi4 ? b : a);
}

__global__ __launch_bounds__(128) void net1_kernel(
    const float* __restrict__ event,
    const int*   __restrict__ lengths,
    const float* __restrict__ W_ih1,
    const float* __restrict__ W_hh1,
    const float* __restrict__ b_ih1,
    const float* __restrict__ b_hh1,
    const float* __restrict__ W_ih2,
    const float* __restrict__ b_ih2,
    const float* __restrict__ b_hh2,
    float* __restrict__ U)
{
    const int p = blockIdx.x;
    const int i = threadIdx.x;                 // output row 0..127

    __shared__ float h[2][HN];                 // double-buffered hidden state
    __shared__ float ev[FN];                   // this particle's input sequence

    ev[i]   = event[p * FN + i];               // coalesced (event is [P,F,1])
    h[0][i] = 0.0f;

    // W_hh1 row i in registers (128 VGPRs) — reused across all steps.
    float w[HN];
    {
        const float4* wrow = reinterpret_cast<const float4*>(W_hh1 + i * HN);
        #pragma unroll
        for (int k = 0; k < HN / 4; ++k) {
            float4 v = wrow[k];
            w[4*k+0] = v.x; w[4*k+1] = v.y; w[4*k+2] = v.z; w[4*k+3] = v.w;
        }
    }
    const float wx   = W_ih1[i];               // W_ih1 is [H,1]
    const float bias = b_ih1[i] + b_hh1[i];
    const int   len  = lengths[p];             // uniform across block, in [1,127)

    __syncthreads();

    // Reference masks updates at t >= len (h frozen) -> just stop at len.
    for (int t = 0; t < len; ++t) {
        const int cur = t & 1;
        const float x = ev[t];                 // LDS broadcast
        float a0 = fmaf(wx, x, bias), a1 = 0.f, a2 = 0.f, a3 = 0.f;
        const float4* h4 = reinterpret_cast<const float4*>(h[cur]);
        #pragma unroll
        for (int k = 0; k < HN / 4; ++k) {
            float4 hv = h4[k];                 // same addr all lanes -> broadcast
            a0 = fmaf(w[4*k+0], hv.x, a0);
            a1 = fmaf(w[4*k+1], hv.y, a1);
            a2 = fmaf(w[4*k+2], hv.z, a2);
            a3 = fmaf(w[4*k+3], hv.w, a3);
        }
        h[cur ^ 1][i] = fast_tanh((a0 + a1) + (a2 + a3));
        lds_barrier();                         // no vmem in flight here; cheap sync
    }

    // Tail: U[p][i] = h1 . W_ih2_row_i + b_ih2[i] + b_hh2[i]  (hoisted out of net2)
    {
        const float4* h4 = reinterpret_cast<const float4*>(h[len & 1]);
        const float4* w2 = reinterpret_cast<const float4*>(W_ih2 + i * HN);
        float a0 = b_ih2[i] + b_hh2[i], a1 = 0.f, a2 = 0.f, a3 = 0.f;
        #pragma unroll
        for (int k = 0; k < HN / 4; ++k) {
            float4 hv = h4[k];
            float4 wv = w2[k];
            a0 = fmaf(wv.x, hv.x, a0);
            a1 = fmaf(wv.y, hv.y, a1);
            a2 = fmaf(wv.z, hv.z, a2);
            a3 = fmaf(wv.w, hv.w, a3);
        }
        U[p * HN + i] = (a0 + a1) + (a2 + a3); // coalesced
    }
}

__global__ __launch_bounds__(256) void net2_kernel(
    const float* __restrict__ U,
    const float* __restrict__ W_hh2,
    float* __restrict__ out)
{
    const int tid  = threadIdx.x;
    const int wv   = tid >> 6;                 // wave 0..3
    const int lane = tid & 63;
    const int jg   = lane & 7;                 // inner group: h slice [jg*16, jg*16+16)
    const int ogl  = lane >> 3;                // output group within wave: 0..7
    const int og   = (wv << 3) + ogl;          // output group 0..31 (4 outputs each)
    const int rot  = jg >> 1;                  // bank-decorrelation rotation 0..3
    const bool hi4 = (jg & 4) != 0;

    // After reduce-scatter this lane holds output og*4 + cidx (pairs jg, jg^1 dup).
    const int cidx = ((jg >> 2) & 1) * 2 + ((jg >> 1) & 1);
    const int oi_w = og * 4 + cidx;

    __shared__ float h[2][HN];                 // double-buffered hidden state
    __shared__ float Ulds[2][CH * HN];         // double-buffered U panel (2 x 32 KB)

    // Weights w[c][4t+e] = W_hh2[og*4+c][jg*16 + 4*((t+rot)&3) + e]: the read
    // rotation is baked into the LOAD order so FMA reg indices stay static.
    float w[4][16];
    #pragma unroll
    for (int c = 0; c < 4; ++c) {
        const float* row = W_hh2 + (og * 4 + c) * HN + jg * 16;
        #pragma unroll
        for (int t = 0; t < 4; ++t) {
            const int krot = (t + rot) & 3;
            float4 v = *reinterpret_cast<const float4*>(row + 4 * krot);
            w[c][4*t+0] = v.x; w[c][4*t+1] = v.y;
            w[c][4*t+2] = v.z; w[c][4*t+3] = v.w;
        }
    }

    // Stage chunk 0 synchronously (8 coalesced float4 per thread).
    {
        const float4* g = reinterpret_cast<const float4*>(U);
        float4*       l = reinterpret_cast<float4*>(&Ulds[0][0]);
        #pragma unroll
        for (int r = 0; r < 8; ++r) l[r * 256 + tid] = g[r * 256 + tid];
    }
    if (tid < HN) h[0][tid] = 0.0f;
    __syncthreads();

    int buf = 0;
    for (int c = 0; c < NCH; ++c) {
        const int nb = buf ^ 1;

        // Issue-early: global loads for chunk c+1 into registers. They stay in
        // flight across the whole chunk (~30K cyc of slack >> HBM latency).
        float4 st[8];
        const int cg = (c + 1 < NCH) ? (c + 1) : c;   // last chunk: harmless reload
        {
            const float4* gsrc = reinterpret_cast<const float4*>(U + cg * CH * HN);
            #pragma unroll
            for (int r = 0; r < 8; ++r) st[r] = gsrc[r * 256 + tid];
        }

        for (int s = 0; s < CH; ++s) {
            const int hc = s & 1;              // CH even -> parity restarts at 0
            const float u_cur = Ulds[buf][s * HN + oi_w];  // ds_read_b32, banks 0..31

            // 4 b128 reads of this lane's 16-float h slice, rotated order ->
            // conflict-free. Each read feeds 16 FMAs.
            const float* base = &h[hc][jg * 16];
            float s0 = 0.f, s1 = 0.f, s2 = 0.f, s3 = 0.f;
            #pragma unroll
            for (int t = 0; t < 4; ++t) {
                const int krot = (t + rot) & 3;    // runtime only in the ADDRESS
                float4 hv = *reinterpret_cast<const float4*>(base + 4 * krot);
                s0 = fmaf(w[0][4*t+0], hv.x, s0); s0 = fmaf(w[0][4*t+1], hv.y, s0);
                s0 = fmaf(w[0][4*t+2], hv.z, s0); s0 = fmaf(w[0][4*t+3], hv.w, s0);
                s1 = fmaf(w[1][4*t+0], hv.x, s1); s1 = fmaf(w[1][4*t+1], hv.y, s1);
                s1 = fmaf(w[1][4*t+2], hv.z, s1); s1 = fmaf(w[1][4*t+3], hv.w, s1);
                s2 = fmaf(w[2][4*t+0], hv.x, s2); s2 = fmaf(w[2][4*t+1], hv.y, s2);
                s2 = fmaf(w[2][4*t+2], hv.z, s2); s2 = fmaf(w[2][4*t+3], hv.w, s2);
                s3 = fmaf(w[3][4*t+0], hv.x, s3); s3 = fmaf(w[3][4*t+1], hv.y, s3);
                s3 = fmaf(w[3][4*t+2], hv.z, s3); s3 = fmaf(w[3][4*t+3], hv.w, s3);
            }

            // Reduce-scatter over the 8 jg lanes — all DPP (VALU), same pairing
            // order as the shfl version (bit-identical sums).
            const bool lo4 = !hi4;
            float t0 = lo4 ? s2 : s0;          // shipped at stage 1
            float t1 = lo4 ? s3 : s1;
            float x0 = (lo4 ? s0 : s2) + dpp_xor4(t0, hi4);
            float x1 = (lo4 ? s1 : s3) + dpp_xor4(t1, hi4);
            const bool lo2 = (jg & 2) == 0;
            float t2 = lo2 ? x1 : x0;          // shipped at stage 2
            float z  = (lo2 ? x0 : x1) + dpp_xor2(t2);
            z += dpp_xor1(z);                  // full sum; pairs jg, jg^1 duplicate

            const float hn = fast_tanh(z + u_cur);
            if ((jg & 1) == 0) h[hc ^ 1][oi_w] = hn;   // 16 lanes/wave, distinct banks
            lds_barrier();                     // lgkm-only: nothing global in flight
        }

        // Write-late: publish staged chunk to the back buffer; vmcnt wait here
        // is ~free (loads issued 64 steps ago). One full barrier per 64 steps.
        {
            float4* ldst = reinterpret_cast<float4*>(&Ulds[nb][0]);
            #pragma unroll
            for (int r = 0; r < 8; ++r) ldst[r * 256 + tid] = st[r];
        }
        __syncthreads();
        buf = nb;
    }

    if (tid < HN) out[tid] = h[0][tid];        // each chunk ends back at parity 0

    // keep weights formally live (paranoia against DCE of the staging pattern)
    asm volatile("" :: "v"(w[0][0]));
}

extern "C" void kernel_launch(void* const* d_in, const int* in_sizes, int n_in,
                              void* d_out, int out_size, void* d_ws, size_t ws_size,
                              hipStream_t stream)
{
    const float* event   = (const float*)d_in[0];
    const int*   lengths = (const int*)  d_in[1];
    const float* W_ih1   = (const float*)d_in[2];
    const float* W_hh1   = (const float*)d_in[3];
    const float* b_ih1   = (const float*)d_in[4];
    const float* b_hh1   = (const float*)d_in[5];
    const float* W_ih2   = (const float*)d_in[6];
    const float* W_hh2   = (const float*)d_in[7];
    const float* b_ih2   = (const float*)d_in[8];
    const float* b_hh2   = (const float*)d_in[9];
    float* out = (float*)d_out;                // 128 floats
    float* U   = (float*)d_ws;                 // PN*HN floats = 2 MB scratch

    hipLaunchKernelGGL(net1_kernel, dim3(PN), dim3(HN), 0, stream,
                       event, lengths, W_ih1, W_hh1, b_ih1, b_hh1,
                       W_ih2, b_ih2, b_hh2, U);
    hipLaunchKernelGGL(net2_kernel, dim3(1), dim3(256), 0, stream,
                       U, W_hh2, out);
}